// Round 13
// baseline (5535.752 us; speedup 1.0000x reference)
//
#include <hip/hip_runtime.h>
#include <hip/hip_bf16.h>

typedef __attribute__((ext_vector_type(8))) short short8;
typedef __attribute__((ext_vector_type(4))) float f32x4;
typedef __attribute__((ext_vector_type(4))) unsigned int u32x4;
typedef __attribute__((ext_vector_type(4))) unsigned short u16x4;

#define T_STEPS 512
#define DIM_D 256
#define DIM_H 512
#define NGROUP 8
#define NCOL 32
#define BB 32
#define SLC 16
#define FSTRIDE 32   // u32 stride between flags: one 128B line each
#define MAXP 20000   // bounded polls: failures finish (wrong), never hang

__device__ __forceinline__ unsigned short f2bf(float f) {
  union { float f; unsigned u; } v; v.f = f;
  unsigned r = v.u + 0x7fffu + ((v.u >> 16) & 1u);
  return (unsigned short)(r >> 16);
}
__device__ __forceinline__ float sigm(float x) { return 1.0f / (1.0f + __expf(-x)); }
__device__ __forceinline__ float tanh_fast(float x) { return 2.0f / (1.0f + __expf(-2.0f * x)) - 1.0f; }

// LLC-coherent (sc0 sc1) primitives
__device__ __forceinline__ void ldg8_bypass(const void* p, u32x4* o) {
  asm volatile(
      "global_load_dwordx4 %0, %8, off sc0 sc1\n\t"
      "global_load_dwordx4 %1, %8, off offset:16 sc0 sc1\n\t"
      "global_load_dwordx4 %2, %8, off offset:32 sc0 sc1\n\t"
      "global_load_dwordx4 %3, %8, off offset:48 sc0 sc1\n\t"
      "global_load_dwordx4 %4, %8, off offset:64 sc0 sc1\n\t"
      "global_load_dwordx4 %5, %8, off offset:80 sc0 sc1\n\t"
      "global_load_dwordx4 %6, %8, off offset:96 sc0 sc1\n\t"
      "global_load_dwordx4 %7, %8, off offset:112 sc0 sc1\n\t"
      "s_waitcnt vmcnt(0)"
      : "=&v"(o[0]), "=&v"(o[1]), "=&v"(o[2]), "=&v"(o[3]),
        "=&v"(o[4]), "=&v"(o[5]), "=&v"(o[6]), "=&v"(o[7])
      : "v"(p)
      : "memory");
}
// LLC-side store: atomic swap, no return
__device__ __forceinline__ void atom_st_u32(unsigned* p, unsigned v) {
  asm volatile("global_atomic_swap %0, %1, off" :: "v"(p), "v"(v) : "memory");
}

__global__ void k_init(unsigned* hx_u32, unsigned* flags) {
  int i = blockIdx.x * 256 + threadIdx.x;
  if (i < 65536) hx_u32[i] = 0u;                     // zero h0 exchange buffer
  if (i < 2 * NGROUP * 64 * FSTRIDE) flags[i] = 0u;  // padded epoch flags (A then B)
}

__global__ void k_packW(const float* __restrict__ W, unsigned short* __restrict__ Wt) {
  int n = blockIdx.x, k = threadIdx.x;    // Wt[n][k] = W[k][n], n<1536, k<256
  Wt[n * 256 + k] = f2bf(W[(size_t)k * 1536 + n]);
}

__global__ void k_packU(const float* __restrict__ U, unsigned short* __restrict__ Ut) {
  int n = blockIdx.x;                     // Ut[n][k] = U[k][n], n<1536, k<512
  for (int k = threadIdx.x; k < 512; k += 256)
    Ut[n * 512 + k] = f2bf(U[(size_t)k * 1536 + n]);
}

__global__ void k_out(const float* __restrict__ part, const float* __restrict__ bd,
                      float* __restrict__ out) {
  int b = threadIdx.x;
  float s = bd[0];
  for (int c = 0; c < 32; c++) s += part[c * 256 + b];
  out[b] = s;
}

__global__ void __launch_bounds__(256, 1)
k_gru(const float* __restrict__ x, const float* __restrict__ bias,
      const float* __restrict__ Wd,
      const unsigned short* __restrict__ Wt, const unsigned short* __restrict__ Ut,
      unsigned short* hx, unsigned short* rhx,
      float* part, unsigned* flags) {
  extern __shared__ char smem[];
  char* sUzr = smem;                      // 32 rows x 1024B (z rows 0-15, r rows 16-31)
  char* sUn  = smem + 32768;              // 16 rows x 1024B
  char* sW   = smem + 49152;              // 48 rows x 512B (z 0-15, r 16-31, n 32-47)
  char* sH   = smem + 73728;              // 32 rows x 1024B  (h / rh staging)
  char* sX   = smem + 106496;             // 32 rows x 512B   (x_t bf16)
  float* sHM = (float*)(smem + 122880);   // 32x16 f32 master h slice
  unsigned* sCnt = (unsigned*)(smem + 124928);  // [0..3]=phase-A chunk counters, [4..7]=B

  const int tid = threadIdx.x;
  const int bid = blockIdx.x;
  const int g = bid & 7;                  // row group (XCD-heuristic for x L2 locality)
  const int c = bid >> 3;                 // column block 0..31 (hidden cols c*16..)
  const int w = tid >> 6;                 // wave 0..3
  const int l = tid & 63;
  const int lrow = l & 15;
  const int lk = l >> 4;
  const int n0 = c * SLC;
  const int mt = w & 1;                   // M-tile (0: rows 0-15, 1: rows 16-31)
  const bool zw = (w < 2);                // waves 0,1: z & n tiles; waves 2,3: r tiles

  unsigned* fA = flags + g * 64 * FSTRIDE;                          // 64 flags/group
  unsigned* fB = flags + NGROUP * 64 * FSTRIDE + g * 64 * FSTRIDE;  // phase B

  unsigned short* hx_g  = hx  + (size_t)g * (BB * DIM_H);
  unsigned short* rhx_g = rhx + (size_t)g * (BB * DIM_H);
  unsigned* hx32_g  = (unsigned*)hx_g;
  unsigned* rhx32_g = (unsigned*)rhx_g;

  // ---- prologue: stage weight slices into LDS (once) ----
  for (int q = tid; q < 2048; q += 256) {         // Uzr slice: 32 rows x 1KB
    int n = q >> 6, ch = q & 63;
    int grow = (n < 16) ? (n0 + n) : (DIM_H + n0 + (n - 16));
    u32x4 v = *(const u32x4*)(Ut + (size_t)grow * DIM_H + ch * 8);
    *(u32x4*)(sUzr + n * 1024 + ((ch * 16) ^ ((n & 7) << 4))) = v;
  }
  for (int q = tid; q < 1024; q += 256) {         // Un slice: 16 rows x 1KB
    int n = q >> 6, ch = q & 63;
    int grow = 2 * DIM_H + n0 + n;
    u32x4 v = *(const u32x4*)(Ut + (size_t)grow * DIM_H + ch * 8);
    *(u32x4*)(sUn + n * 1024 + ((ch * 16) ^ ((n & 7) << 4))) = v;
  }
  for (int q = tid; q < 1536; q += 256) {         // W slice: 48 rows x 512B
    int n = q >> 5, ch = q & 31;
    int grow = (n < 16) ? (n0 + n) : (n < 32 ? (DIM_H + n0 + (n - 16))
                                             : (2 * DIM_H + n0 + (n - 32)));
    u32x4 v = *(const u32x4*)(Wt + (size_t)grow * DIM_D + ch * 8);
    *(u32x4*)(sW + n * 512 + ((ch * 16) ^ ((n & 7) << 4))) = v;
  }
  sHM[tid] = 0.0f; sHM[tid + 256] = 0.0f;
  if (tid < 8) sCnt[tid] = 0u;
  const float bz_l = bias[n0 + lrow];
  const float br_l = bias[DIM_H + n0 + lrow];
  const float bn_l = bias[2 * DIM_H + n0 + lrow];
  __syncthreads();

  f32x4 azr, an;

  auto stage_x = [&](int t) {
    const int xr = tid >> 3;
    const int xj = (tid & 7) * 32;
    const float* xp = x + ((size_t)(g * BB + xr) * T_STEPS + t) * DIM_D + xj;
#pragma unroll
    for (int i = 0; i < 8; i++) {
      float4 v = ((const float4*)xp)[i];
      u16x4 h4 = { f2bf(v.x), f2bf(v.y), f2bf(v.z), f2bf(v.w) };
      int kb = (xj + i * 4) * 2;
      *(u16x4*)(sX + xr * 512 + (kb ^ ((xr & 7) << 4))) = h4;
    }
  };

  auto w_mfma = [&]() {   // seeds accumulators for a step: bias + x_t @ W-slice
    float bini = zw ? bz_l : br_l;
    f32x4 t0 = { bini, bini, bini, bini };
    azr = t0;
    f32x4 t1 = { bn_l, bn_l, bn_l, bn_l };
    an = t1;
    const int arow = mt * 16 + lrow;
    const int nzr = zw ? lrow : (16 + lrow);
    const int nnn = 32 + lrow;
#pragma unroll
    for (int ks = 0; ks < 8; ks++) {
      int kb = ks * 64 + lk * 16;
      short8 a = *(const short8*)(sX + arow * 512 + (kb ^ ((arow & 7) << 4)));
      short8 b0 = *(const short8*)(sW + nzr * 512 + (kb ^ ((nzr & 7) << 4)));
      azr = __builtin_amdgcn_mfma_f32_16x16x32_bf16(a, b0, azr, 0, 0, 0);
      if (zw) {
        short8 b1 = *(const short8*)(sW + nnn * 512 + (kb ^ ((nnn & 7) << 4)));
        an = __builtin_amdgcn_mfma_f32_16x16x32_bf16(a, b1, an, 0, 0, 0);
      }
    }
  };

  // Poll own strip's 4 flags, stage the 128B strip into sH, bump chunk counter.
  // Chunk = ck>>1 (128 cols); counter is monotonic (target 64*(t+1)).
  auto pollstage = [&](const unsigned short* src_base, unsigned* f, unsigned e, int ph) {
    const int hr = tid >> 3;                       // row 0..31
    const int ck = tid & 7;                        // 64-col strip within row
    const int half = hr >> 4;
    const unsigned* fp = f + (((unsigned)(ck << 3)) | half) * FSTRIDE;
    for (int it = 0; it < MAXP; ++it) {
      unsigned a0, a1, a2, a3;
      asm volatile(
          "global_load_dword %0, %4, off sc0 sc1\n\t"
          "global_load_dword %1, %4, off offset:256 sc0 sc1\n\t"
          "global_load_dword %2, %4, off offset:512 sc0 sc1\n\t"
          "global_load_dword %3, %4, off offset:768 sc0 sc1\n\t"
          "s_waitcnt vmcnt(0)"
          : "=&v"(a0), "=&v"(a1), "=&v"(a2), "=&v"(a3)
          : "v"(fp)
          : "memory");
      if (a0 >= e && a1 >= e && a2 >= e && a3 >= e) break;
      __builtin_amdgcn_s_sleep(1);
    }
    const char* s0 = (const char*)(src_base + hr * DIM_H) + ck * 128;
    u32x4 v[8];
    ldg8_bypass(s0, v);
    char* dst = sH + hr * 1024;
    const int sw = (hr & 7) << 4;
#pragma unroll
    for (int i = 0; i < 8; i++)
      *(u32x4*)(dst + ((ck * 128 + i * 16) ^ sw)) = v[i];
    __hip_atomic_fetch_add(sCnt + ph * 4 + (ck >> 1), 1u,
                           __ATOMIC_RELEASE, __HIP_MEMORY_SCOPE_WORKGROUP);
  };

  auto chunk_spin = [&](int ph, int k, unsigned tgt) {
    volatile unsigned* cp = sCnt + ph * 4 + k;
    for (int it = 0; it < (1 << 20); ++it) {
      if (*cp >= tgt) break;
      __builtin_amdgcn_s_sleep(1);
    }
    asm volatile("" ::: "memory");   // no sH reads hoisted above the spin
  };

  auto uzr_chunk = [&](int k) {      // 4 ks (=128 cols) of the Uzr matmul
    const int arow = mt * 16 + lrow;
    const int n = zw ? lrow : (16 + lrow);
#pragma unroll
    for (int ks = 4 * k; ks < 4 * k + 4; ks++) {
      int kb = ks * 64 + lk * 16;
      short8 a = *(const short8*)(sH + arow * 1024 + (kb ^ ((arow & 7) << 4)));
      short8 b8 = *(const short8*)(sUzr + n * 1024 + (kb ^ ((n & 7) << 4)));
      azr = __builtin_amdgcn_mfma_f32_16x16x32_bf16(a, b8, azr, 0, 0, 0);
    }
  };

  auto un_chunk = [&](int k) {
    const int arow = mt * 16 + lrow;
#pragma unroll
    for (int ks = 4 * k; ks < 4 * k + 4; ks++) {
      int kb = ks * 64 + lk * 16;
      short8 a = *(const short8*)(sH + arow * 1024 + (kb ^ ((arow & 7) << 4)));
      short8 b8 = *(const short8*)(sUn + lrow * 1024 + (kb ^ ((lrow & 7) << 4)));
      an = __builtin_amdgcn_mfma_f32_16x16x32_bf16(a, b8, an, 0, 0, 0);
    }
  };

  stage_x(0);
  __syncthreads();
  w_mfma();

  for (int t = 0; t < T_STEPS; t++) {
    const unsigned e1 = (unsigned)(t + 1);
    const unsigned tgt = 64u * e1;

    // ---- phase A: sH := h_{t-1} (chunk-streamed); z,r; r-waves publish r*h ----
    pollstage(hx_g, fB, (unsigned)t, 0);   // t=0: flags 0>=0, data = k_init zeros
    for (int k = 0; k < 4; k++) { chunk_spin(0, k, tgt); uzr_chunk(k); }
    if (!zw) {                             // r-waves: pack bf16 pairs, publish
#pragma unroll
      for (int j = 0; j < 4; j++) {
        int row = mt * 16 + lk * 4 + j;
        float rv = sigm(azr[j]);
        unsigned mv = (unsigned)f2bf(rv * sHM[row * 16 + lrow]);
        unsigned nb = (unsigned)__shfl_xor((int)mv, 1, 64) & 0xFFFFu;
        if (!(lrow & 1))
          atom_st_u32(rhx32_g + row * 256 + ((n0 + lrow) >> 1), mv | (nb << 16));
      }
    }
    __syncthreads();                       // S2: sH reads done; sH reusable
    if (!zw) {                             // drain + flag AFTER S2
      asm volatile("s_waitcnt vmcnt(0)" ::: "memory");
      if (l == 0) atom_st_u32(fA + ((c << 1) | mt) * FSTRIDE, e1);
    }

    // ---- phase B: sH := (r.h)_t (chunk-streamed); n, h_new; z-waves publish h ----
    pollstage(rhx_g, fA, e1, 1);
    if (zw) {
      for (int k = 0; k < 4; k++) { chunk_spin(1, k, tgt); un_chunk(k); }
#pragma unroll
      for (int j = 0; j < 4; j++) {
        int row = mt * 16 + lk * 4 + j;
        float zv = sigm(azr[j]);
        float nv = tanh_fast(an[j]);
        float hv = sHM[row * 16 + lrow];
        float hn = zv * hv + (1.0f - zv) * nv;
        sHM[row * 16 + lrow] = hn;
        if (t + 1 < T_STEPS) {
          unsigned mv = (unsigned)f2bf(hn);
          unsigned nb = (unsigned)__shfl_xor((int)mv, 1, 64) & 0xFFFFu;
          if (!(lrow & 1))
            atom_st_u32(hx32_g + row * 256 + ((n0 + lrow) >> 1), mv | (nb << 16));
        }
      }
    }
    if (t + 1 < T_STEPS) stage_x(t + 1);   // overlaps z-waves' atomic drain
    if (zw && t + 1 < T_STEPS) {
      asm volatile("s_waitcnt vmcnt(0)" ::: "memory");
      if (l == 0) atom_st_u32(fB + ((c << 1) | mt) * FSTRIDE, e1);
    }
    __syncthreads();                       // S4: sX ready, sHM updated, sH reads done
    if (t + 1 < T_STEPS) w_mfma();         // overlaps h propagation
  }

  // ---- epilogue: partial of h_last @ Wd ----
  if (tid < BB) {
    float s = 0.0f;
#pragma unroll
    for (int i = 0; i < SLC; i++) s += sHM[tid * 16 + i] * Wd[n0 + i];
    part[c * 256 + g * BB + tid] = s;
  }
}

extern "C" void kernel_launch(void* const* d_in, const int* in_sizes, int n_in,
                              void* d_out, int out_size, void* d_ws, size_t ws_size,
                              hipStream_t stream) {
  const float* x    = (const float*)d_in[0];
  const float* W    = (const float*)d_in[1];
  const float* U    = (const float*)d_in[2];
  const float* bias = (const float*)d_in[3];
  const float* Wd   = (const float*)d_in[4];
  const float* bd   = (const float*)d_in[5];
  float* out = (float*)d_out;
  char* ws = (char*)d_ws;

  unsigned short* Wt  = (unsigned short*)(ws + 0);        // 1536x256 bf16
  unsigned short* Ut  = (unsigned short*)(ws + 786432);   // 1536x512 bf16
  unsigned short* hx  = (unsigned short*)(ws + 2359296);  // 8x32x512 bf16
  unsigned short* rhx = (unsigned short*)(ws + 2621440);  // 8x32x512 bf16
  float* part         = (float*)(ws + 2883584);           // 32x256 f32
  unsigned* flags     = (unsigned*)(ws + 2916352);        // 2*8*64 padded flags (128KB)

  hipFuncSetAttribute((const void*)k_gru, hipFuncAttributeMaxDynamicSharedMemorySize, 124992);

  k_init<<<256, 256, 0, stream>>>((unsigned*)hx, flags);
  k_packW<<<1536, 256, 0, stream>>>(W, Wt);
  k_packU<<<1536, 256, 0, stream>>>(U, Ut);
  k_gru<<<256, 256, 124992, stream>>>(x, bias, Wd, Wt, Ut, hx, rhx, part, flags);
  k_out<<<1, 256, 0, stream>>>(part, bd, out);
}

// Round 14
// 4953.482 us; speedup vs baseline: 1.1175x; 1.1175x over previous
//
#include <hip/hip_runtime.h>
#include <hip/hip_bf16.h>

typedef __attribute__((ext_vector_type(8))) short short8;
typedef __attribute__((ext_vector_type(4))) float f32x4;
typedef __attribute__((ext_vector_type(4))) unsigned int u32x4;
typedef __attribute__((ext_vector_type(4))) unsigned short u16x4;

#define T_STEPS 512
#define DIM_D 256
#define DIM_H 512
#define NGROUP 8
#define NCOL 32
#define BB 32
#define SLC 16
#define FSTRIDE 32   // u32 stride between flags: one 128B line each
#define MAXP 16384   // bounded poll: any protocol failure -> finite run, never a hang

__device__ __forceinline__ unsigned short f2bf(float f) {
  union { float f; unsigned u; } v; v.f = f;
  unsigned r = v.u + 0x7fffu + ((v.u >> 16) & 1u);
  return (unsigned short)(r >> 16);
}
__device__ __forceinline__ float sigm(float x) { return 1.0f / (1.0f + __expf(-x)); }
__device__ __forceinline__ float tanh_fast(float x) { return 2.0f / (1.0f + __expf(-2.0f * x)) - 1.0f; }

// LLC-coherent (sc0 sc1) primitives — the proven-safe cross-CU visibility path.
__device__ __forceinline__ void ldg8_bypass(const void* p, u32x4* o) {
  asm volatile(
      "global_load_dwordx4 %0, %8, off sc0 sc1\n\t"
      "global_load_dwordx4 %1, %8, off offset:16 sc0 sc1\n\t"
      "global_load_dwordx4 %2, %8, off offset:32 sc0 sc1\n\t"
      "global_load_dwordx4 %3, %8, off offset:48 sc0 sc1\n\t"
      "global_load_dwordx4 %4, %8, off offset:64 sc0 sc1\n\t"
      "global_load_dwordx4 %5, %8, off offset:80 sc0 sc1\n\t"
      "global_load_dwordx4 %6, %8, off offset:96 sc0 sc1\n\t"
      "global_load_dwordx4 %7, %8, off offset:112 sc0 sc1\n\t"
      "s_waitcnt vmcnt(0)"
      : "=&v"(o[0]), "=&v"(o[1]), "=&v"(o[2]), "=&v"(o[3]),
        "=&v"(o[4]), "=&v"(o[5]), "=&v"(o[6]), "=&v"(o[7])
      : "v"(p)
      : "memory");
}
// LLC-side store: atomic swap, no return
__device__ __forceinline__ void atom_st_u32(unsigned* p, unsigned v) {
  asm volatile("global_atomic_swap %0, %1, off" :: "v"(p), "v"(v) : "memory");
}

__global__ void k_init(unsigned* hx_u32, unsigned* flags) {
  int i = blockIdx.x * 256 + threadIdx.x;
  if (i < 65536) hx_u32[i] = 0u;                     // zero h0 exchange buffer
  if (i < 2 * NGROUP * 64 * FSTRIDE) flags[i] = 0u;  // padded epoch flags (A then B)
}

__global__ void k_packW(const float* __restrict__ W, unsigned short* __restrict__ Wt) {
  int n = blockIdx.x, k = threadIdx.x;    // Wt[n][k] = W[k][n], n<1536, k<256
  Wt[n * 256 + k] = f2bf(W[(size_t)k * 1536 + n]);
}

__global__ void k_packU(const float* __restrict__ U, unsigned short* __restrict__ Ut) {
  int n = blockIdx.x;                     // Ut[n][k] = U[k][n], n<1536, k<512
  for (int k = threadIdx.x; k < 512; k += 256)
    Ut[n * 512 + k] = f2bf(U[(size_t)k * 1536 + n]);
}

__global__ void k_out(const float* __restrict__ part, const float* __restrict__ bd,
                      float* __restrict__ out) {
  int b = threadIdx.x;
  float s = bd[0];
  for (int c = 0; c < 32; c++) s += part[c * 256 + b];
  out[b] = s;
}

__global__ void __launch_bounds__(256, 1)
k_gru(const float* __restrict__ x, const float* __restrict__ bias,
      const float* __restrict__ Wd,
      const unsigned short* __restrict__ Wt, const unsigned short* __restrict__ Ut,
      unsigned short* hx, unsigned short* rhx,
      float* part, unsigned* flags) {
  extern __shared__ char smem[];
  char* sUzr = smem;                      // 32 rows x 1024B (z rows 0-15, r rows 16-31)
  char* sUn  = smem + 32768;              // 16 rows x 1024B
  char* sW   = smem + 49152;              // 48 rows x 512B (z 0-15, r 16-31, n 32-47)
  char* sH   = smem + 73728;              // 32 rows x 1024B  (h / rh staging)
  char* sX   = smem + 106496;             // 32 rows x 512B   (x_t bf16)
  float* sHM = (float*)(smem + 122880);   // 32x16 f32 master h slice

  const int tid = threadIdx.x;
  const int bid = blockIdx.x;
  const int g = bid & 7;                  // row group (XCD-heuristic for x L2 locality)
  const int c = bid >> 3;                 // column block 0..31 (hidden cols c*16..)
  const int w = tid >> 6;                 // wave 0..3
  const int l = tid & 63;
  const int lrow = l & 15;
  const int lk = l >> 4;
  const int n0 = c * SLC;
  const int mt = w & 1;                   // M-tile (0: rows 0-15, 1: rows 16-31)
  const bool zw = (w < 2);                // waves 0,1: z & n tiles; waves 2,3: r tiles

  unsigned* fA = flags + g * 64 * FSTRIDE;                          // 64 flags/group
  unsigned* fB = flags + NGROUP * 64 * FSTRIDE + g * 64 * FSTRIDE;  // phase B

  unsigned short* hx_g  = hx  + (size_t)g * (BB * DIM_H);
  unsigned short* rhx_g = rhx + (size_t)g * (BB * DIM_H);
  unsigned* hx32_g  = (unsigned*)hx_g;
  unsigned* rhx32_g = (unsigned*)rhx_g;

  // ---- prologue: stage weight slices into LDS (once) ----
  for (int q = tid; q < 2048; q += 256) {         // Uzr slice: 32 rows x 1KB
    int n = q >> 6, ch = q & 63;
    int grow = (n < 16) ? (n0 + n) : (DIM_H + n0 + (n - 16));
    u32x4 v = *(const u32x4*)(Ut + (size_t)grow * DIM_H + ch * 8);
    *(u32x4*)(sUzr + n * 1024 + ((ch * 16) ^ ((n & 7) << 4))) = v;
  }
  for (int q = tid; q < 1024; q += 256) {         // Un slice: 16 rows x 1KB
    int n = q >> 6, ch = q & 63;
    int grow = 2 * DIM_H + n0 + n;
    u32x4 v = *(const u32x4*)(Ut + (size_t)grow * DIM_H + ch * 8);
    *(u32x4*)(sUn + n * 1024 + ((ch * 16) ^ ((n & 7) << 4))) = v;
  }
  for (int q = tid; q < 1536; q += 256) {         // W slice: 48 rows x 512B
    int n = q >> 5, ch = q & 31;
    int grow = (n < 16) ? (n0 + n) : (n < 32 ? (DIM_H + n0 + (n - 16))
                                             : (2 * DIM_H + n0 + (n - 32)));
    u32x4 v = *(const u32x4*)(Wt + (size_t)grow * DIM_D + ch * 8);
    *(u32x4*)(sW + n * 512 + ((ch * 16) ^ ((n & 7) << 4))) = v;
  }
  sHM[tid] = 0.0f; sHM[tid + 256] = 0.0f;
  const float bz_l = bias[n0 + lrow];
  const float br_l = bias[DIM_H + n0 + lrow];
  const float bn_l = bias[2 * DIM_H + n0 + lrow];
  __syncthreads();

  f32x4 azr, an;

  auto stage_x = [&](int t) {
    const int xr = tid >> 3;
    const int xj = (tid & 7) * 32;
    const float* xp = x + ((size_t)(g * BB + xr) * T_STEPS + t) * DIM_D + xj;
#pragma unroll
    for (int i = 0; i < 8; i++) {
      float4 v = ((const float4*)xp)[i];
      u16x4 h4 = { f2bf(v.x), f2bf(v.y), f2bf(v.z), f2bf(v.w) };
      int kb = (xj + i * 4) * 2;
      *(u16x4*)(sX + xr * 512 + (kb ^ ((xr & 7) << 4))) = h4;
    }
  };

  auto w_mfma = [&]() {   // seeds accumulators for a step: bias + x_t @ W-slice
    float bini = zw ? bz_l : br_l;
    f32x4 t0 = { bini, bini, bini, bini };
    azr = t0;
    f32x4 t1 = { bn_l, bn_l, bn_l, bn_l };
    an = t1;
    const int arow = mt * 16 + lrow;
    const int nzr = zw ? lrow : (16 + lrow);
    const int nnn = 32 + lrow;
#pragma unroll
    for (int ks = 0; ks < 8; ks++) {
      int kb = ks * 64 + lk * 16;
      short8 a = *(const short8*)(sX + arow * 512 + (kb ^ ((arow & 7) << 4)));
      short8 b0 = *(const short8*)(sW + nzr * 512 + (kb ^ ((nzr & 7) << 4)));
      azr = __builtin_amdgcn_mfma_f32_16x16x32_bf16(a, b0, azr, 0, 0, 0);
      if (zw) {
        short8 b1 = *(const short8*)(sW + nnn * 512 + (kb ^ ((nnn & 7) << 4)));
        an = __builtin_amdgcn_mfma_f32_16x16x32_bf16(a, b1, an, 0, 0, 0);
      }
    }
  };

  // Fused per-thread poll+load: poll the 4 flags covering this thread's 128B strip,
  // then immediately issue the strip load and write it swizzled into sH.
  auto pollload = [&](const unsigned short* src_base, unsigned* f, unsigned e) {
    const int hr = tid >> 3;                       // row 0..31
    const int ck = tid & 7;                        // 128B strip within row
    const int half = hr >> 4;
    const unsigned* fp = f + (((unsigned)(ck << 3)) | half) * FSTRIDE;
    for (int it = 0; it < MAXP; ++it) {
      unsigned a0, a1, a2, a3;
      asm volatile(
          "global_load_dword %0, %4, off sc0 sc1\n\t"
          "global_load_dword %1, %4, off offset:256 sc0 sc1\n\t"
          "global_load_dword %2, %4, off offset:512 sc0 sc1\n\t"
          "global_load_dword %3, %4, off offset:768 sc0 sc1\n\t"
          "s_waitcnt vmcnt(0)"
          : "=&v"(a0), "=&v"(a1), "=&v"(a2), "=&v"(a3)
          : "v"(fp)
          : "memory");
      if (a0 >= e && a1 >= e && a2 >= e && a3 >= e) break;
      __builtin_amdgcn_s_sleep(1);
    }
    const char* s0 = (const char*)(src_base + hr * DIM_H) + ck * 128;
    u32x4 v[8];
    ldg8_bypass(s0, v);
    char* dst = sH + hr * 1024;
    const int sw = (hr & 7) << 4;
#pragma unroll
    for (int i = 0; i < 8; i++)
      *(u32x4*)(dst + ((ck * 128 + i * 16) ^ sw)) = v[i];
  };

  auto uzr_mfma = [&]() {
    const int arow = mt * 16 + lrow;
    const int n = zw ? lrow : (16 + lrow);
#pragma unroll
    for (int ks = 0; ks < 16; ks++) {
      int kb = ks * 64 + lk * 16;
      short8 a = *(const short8*)(sH + arow * 1024 + (kb ^ ((arow & 7) << 4)));
      short8 b8 = *(const short8*)(sUzr + n * 1024 + (kb ^ ((n & 7) << 4)));
      azr = __builtin_amdgcn_mfma_f32_16x16x32_bf16(a, b8, azr, 0, 0, 0);
    }
  };

  auto un_mfma = [&]() {
    const int arow = mt * 16 + lrow;
#pragma unroll
    for (int ks = 0; ks < 16; ks++) {
      int kb = ks * 64 + lk * 16;
      short8 a = *(const short8*)(sH + arow * 1024 + (kb ^ ((arow & 7) << 4)));
      short8 b8 = *(const short8*)(sUn + lrow * 1024 + (kb ^ ((lrow & 7) << 4)));
      an = __builtin_amdgcn_mfma_f32_16x16x32_bf16(a, b8, an, 0, 0, 0);
    }
  };

  stage_x(0);
  __syncthreads();
  w_mfma();

  for (int t = 0; t < T_STEPS; t++) {
    const unsigned e1 = (unsigned)(t + 1);

    // ---- phase A: sH := h_{t-1}; z,r = sigm(...); r-waves publish r*h ----
    pollload(hx_g, fB, (unsigned)t);   // t=0: flags 0 >= 0, data = k_init zeros
    __syncthreads();                   // S1: sH ready
    uzr_mfma();
    if (!zw) {                         // r-waves: pack bf16 pairs, publish
#pragma unroll
      for (int j = 0; j < 4; j++) {
        int row = mt * 16 + lk * 4 + j;
        float rv = sigm(azr[j]);
        unsigned mv = (unsigned)f2bf(rv * sHM[row * 16 + lrow]);
        unsigned nb = (unsigned)__shfl_xor((int)mv, 1, 64) & 0xFFFFu;
        if (!(lrow & 1))
          atom_st_u32(rhx32_g + row * 256 + ((n0 + lrow) >> 1), mv | (nb << 16));
      }
    }
    __syncthreads();                   // S2: all uzr reads of sH done; sH reusable
    if (!zw) {                         // drain + flag AFTER S2 (overlaps others' poll)
      asm volatile("s_waitcnt vmcnt(0)" ::: "memory");
      if (l == 0) atom_st_u32(fA + ((c << 1) | mt) * FSTRIDE, e1);
    }

    // ---- phase B: sH := (r.h)_t; n = tanh(...); h_new; z-waves publish h ----
    pollload(rhx_g, fA, e1);
    __syncthreads();                   // S3: sH ready
    if (zw) {
      un_mfma();
#pragma unroll
      for (int j = 0; j < 4; j++) {
        int row = mt * 16 + lk * 4 + j;
        float zv = sigm(azr[j]);
        float nv = tanh_fast(an[j]);
        float hv = sHM[row * 16 + lrow];
        float hn = zv * hv + (1.0f - zv) * nv;
        sHM[row * 16 + lrow] = hn;
        if (t + 1 < T_STEPS) {
          unsigned mv = (unsigned)f2bf(hn);
          unsigned nb = (unsigned)__shfl_xor((int)mv, 1, 64) & 0xFFFFu;
          if (!(lrow & 1))
            atom_st_u32(hx32_g + row * 256 + ((n0 + lrow) >> 1), mv | (nb << 16));
        }
      }
    }
    if (t + 1 < T_STEPS) stage_x(t + 1);   // overlaps z-waves' atomic drain
    if (zw && t + 1 < T_STEPS) {
      asm volatile("s_waitcnt vmcnt(0)" ::: "memory");
      if (l == 0) atom_st_u32(fB + ((c << 1) | mt) * FSTRIDE, e1);
    }
    __syncthreads();                   // S4: sX ready, sHM updated, sH reads done
    if (t + 1 < T_STEPS) w_mfma();     // overlaps h propagation; next pollload gates
  }

  // ---- epilogue: partial of h_last @ Wd ----
  if (tid < BB) {
    float s = 0.0f;
#pragma unroll
    for (int i = 0; i < SLC; i++) s += sHM[tid * 16 + i] * Wd[n0 + i];
    part[c * 256 + g * BB + tid] = s;
  }
}

extern "C" void kernel_launch(void* const* d_in, const int* in_sizes, int n_in,
                              void* d_out, int out_size, void* d_ws, size_t ws_size,
                              hipStream_t stream) {
  const float* x    = (const float*)d_in[0];
  const float* W    = (const float*)d_in[1];
  const float* U    = (const float*)d_in[2];
  const float* bias = (const float*)d_in[3];
  const float* Wd   = (const float*)d_in[4];
  const float* bd   = (const float*)d_in[5];
  float* out = (float*)d_out;
  char* ws = (char*)d_ws;

  unsigned short* Wt  = (unsigned short*)(ws + 0);        // 1536x256 bf16
  unsigned short* Ut  = (unsigned short*)(ws + 786432);   // 1536x512 bf16
  unsigned short* hx  = (unsigned short*)(ws + 2359296);  // 8x32x512 bf16
  unsigned short* rhx = (unsigned short*)(ws + 2621440);  // 8x32x512 bf16
  float* part         = (float*)(ws + 2883584);           // 32x256 f32
  unsigned* flags     = (unsigned*)(ws + 2916352);        // 2*8*64 padded flags (128KB)

  hipFuncSetAttribute((const void*)k_gru, hipFuncAttributeMaxDynamicSharedMemorySize, 124928);

  k_init<<<256, 256, 0, stream>>>((unsigned*)hx, flags);
  k_packW<<<1536, 256, 0, stream>>>(W, Wt);
  k_packU<<<1536, 256, 0, stream>>>(U, Ut);
  k_gru<<<256, 256, 124928, stream>>>(x, bias, Wd, Wt, Ut, hx, rhx, part, flags);
  k_out<<<1, 256, 0, stream>>>(part, bd, out);
}